// Round 2
// baseline (616.174 us; speedup 1.0000x reference)
//
#include <hip/hip_runtime.h>
#include <stdint.h>

#define B_ 4
#define C_ 256
#define N_ 4096
#define TK 32

using floatx4 = __attribute__((ext_vector_type(4))) float;
using halfx8  = __attribute__((ext_vector_type(8))) _Float16;

__device__ __forceinline__ float bf16_to_f(uint16_t u) {
    union { uint32_t u; float f; } c; c.u = ((uint32_t)u) << 16; return c.f;
}
__device__ __forceinline__ uint16_t f_to_bf16(float f) {
    union { float f; uint32_t u; } c; c.f = f;
    uint32_t u = c.u;
    u += 0x7FFFu + ((u >> 16) & 1u);   // RNE
    return (uint16_t)(u >> 16);
}

// ---------------- Kernel -1: sniff input dtype ----------------
// True-bf16 Wq (sigma=1/16): no element has |v|>=32. f32 bits read as bf16:
// ~24% of u16s have bf16-exponent >= 132. Writes flag: 1 = inputs are f32.
__global__ void sniff_kernel(const uint16_t* __restrict__ wq_u16, int* __restrict__ flag) {
    __shared__ int cnt;
    if (threadIdx.x == 0) cnt = 0;
    __syncthreads();
    int local = 0;
    for (int i = threadIdx.x; i < 8192; i += 256) {
        int e = (wq_u16[i] >> 7) & 0xFF;
        if (e >= 132) local++;
    }
    atomicAdd(&cnt, local);
    __syncthreads();
    if (threadIdx.x == 0) *flag = (cnt > 64) ? 1 : 0;
}

// ---------------- Kernel 0: convert W -> f16 in workspace ----------------
__global__ void wconv_kernel(const void* __restrict__ wq,
                             const void* __restrict__ wk,
                             const void* __restrict__ wv,
                             _Float16* __restrict__ wf,
                             const int* __restrict__ flag) {
    const int isf32 = *flag;
    int idx = blockIdx.x * 256 + threadIdx.x;      // 0..196607
    int mat = idx >> 16;
    int off = idx & 65535;
    const void* src = (mat == 0) ? wq : ((mat == 1) ? wk : wv);
    float v = isf32 ? ((const float*)src)[off] : bf16_to_f(((const uint16_t*)src)[off]);
    wf[idx] = (_Float16)v;
}

// ---------------- Kernel 1: QKV projection (MFMA f16) ----------------
// Q = Wq*X etc. Stores Qt,Kt as (B,N,C) f16 (transposed), V as (B,C,N) f16.
__global__ __launch_bounds__(256) void proj_kernel(
    const void* __restrict__ x_raw,      // (B,C,N) bf16 or f32
    const _Float16* __restrict__ wf,     // 3 x (C,C) f16
    _Float16* __restrict__ qt,           // (B,N,C)
    _Float16* __restrict__ kt,           // (B,N,C)
    _Float16* __restrict__ v,            // (B,C,N)
    const int* __restrict__ flag) {
    const int isf32 = *flag;
    const int b = blockIdx.y;
    const int n0 = blockIdx.x * 64;
    const int tid = threadIdx.x;
    const int w = tid >> 6;
    const int L = tid & 63;
    const int lane15 = L & 15;
    const int quad = L >> 4;
    const int n = n0 + w * 16 + lane15;           // this wave's N column (B-frag n = lane&15)

    // Preload B-frags: B[k=c][n], lane holds c = cs*32 + quad*8 + j
    halfx8 bfrag[8];
    const size_t xbase = (size_t)b * C_ * N_;
    if (isf32) {
        const float* xb = (const float*)x_raw + xbase;
#pragma unroll
        for (int cs = 0; cs < 8; ++cs) {
            const int cbase = cs * 32 + quad * 8;
            halfx8 f;
#pragma unroll
            for (int j = 0; j < 8; ++j)
                f[j] = (_Float16)xb[(size_t)(cbase + j) * N_ + n];
            bfrag[cs] = f;
        }
    } else {
        const uint16_t* xb = (const uint16_t*)x_raw + xbase;
#pragma unroll
        for (int cs = 0; cs < 8; ++cs) {
            const int cbase = cs * 32 + quad * 8;
            halfx8 f;
#pragma unroll
            for (int j = 0; j < 8; ++j)
                f[j] = (_Float16)bf16_to_f(xb[(size_t)(cbase + j) * N_ + n]);
            bfrag[cs] = f;
        }
    }

    for (int mat = 0; mat < 3; ++mat) {
        const _Float16* wm = wf + mat * (C_ * C_);
#pragma unroll 4
        for (int ot = 0; ot < 16; ++ot) {
            const int obase = ot * 16;
            floatx4 acc = {0.f, 0.f, 0.f, 0.f};
            const _Float16* wrow = wm + (size_t)(obase + lane15) * C_ + quad * 8;
#pragma unroll
            for (int cs = 0; cs < 8; ++cs) {
                halfx8 af = *(const halfx8*)(wrow + cs * 32);
                acc = __builtin_amdgcn_mfma_f32_16x16x32_f16(af, bfrag[cs], acc, 0, 0, 0);
            }
            // D[o][n]: col n = lane15, row o = obase + quad*4 + r
            if (mat < 2) {
                _Float16* dst = (mat == 0 ? qt : kt) +
                                ((size_t)b * N_ + n) * C_ + obase + quad * 4;
                union { _Float16 h[4]; unsigned long long u64; } pk;
#pragma unroll
                for (int r = 0; r < 4; ++r) pk.h[r] = (_Float16)acc[r];
                *(unsigned long long*)dst = pk.u64;
            } else {
                _Float16* dst = v + ((size_t)b * C_ + obase + quad * 4) * N_ + n;
#pragma unroll
                for (int r = 0; r < 4; ++r) dst[(size_t)r * N_] = (_Float16)acc[r];
            }
        }
    }
}

// ---------------- Kernel 2: flash attention + epilogue ----------------
// Block: (b, 64-query tile). 4 waves x 16 queries each; softmax fully wave-local.
__global__ __launch_bounds__(256, 2) void attn_kernel(
    const void* __restrict__ x_raw,      // (B,C,N) bf16 or f32
    const _Float16* __restrict__ qt,     // (B,N,C)
    const _Float16* __restrict__ kt,     // (B,N,C)
    const _Float16* __restrict__ v,      // (B,C,N)
    const void* __restrict__ gamma_p,
    void* __restrict__ out,              // (B,C,N) bf16 or f32
    const int* __restrict__ flag) {
    const int isf32 = *flag;
    const int b = blockIdx.y;
    const int q0 = blockIdx.x * 64;
    const int tid = threadIdx.x;
    const int w = tid >> 6;
    const int L = tid & 63;
    const int lane15 = L & 15;
    const int quad = L >> 4;

    __shared__ _Float16 Kt_s[TK][264];       // [key][c], row +8B -> 2-way bank alias (free)
    __shared__ _Float16 Vs[C_][40];          // [c][key]
    __shared__ _Float16 Ps[4][16][40];       // per-wave P: [q][key]
    __shared__ float alpha_s[4][16];
    __shared__ float l_s[4][16];

    // Q A-frags (wave-resident): A[m=q][k=c]
    halfx8 qfrag[8];
    {
        const _Float16* qrow = qt + ((size_t)b * N_ + q0 + w * 16 + lane15) * C_ + quad * 8;
#pragma unroll
        for (int cs = 0; cs < 8; ++cs) qfrag[cs] = *(const halfx8*)(qrow + cs * 32);
    }

    floatx4 o_acc[16];
#pragma unroll
    for (int i = 0; i < 16; ++i) o_acc[i] = (floatx4){0.f, 0.f, 0.f, 0.f};
    float m_r[4], l_r[4];
#pragma unroll
    for (int r = 0; r < 4; ++r) { m_r[r] = -1e30f; l_r[r] = 0.f; }

    const _Float16* ktb = kt + (size_t)b * N_ * C_;
    const _Float16* vb  = v  + (size_t)b * C_ * N_;

    for (int k0 = 0; k0 < N_; k0 += TK) {
        // ---- stage K tile (32 x 256) and V tile (256 x 32) ----
#pragma unroll
        for (int p = 0; p < 4; ++p) {
            int idx = p * 256 + tid;             // 0..1023 16B-chunks
            int key = idx >> 5;
            int ch  = idx & 31;
            halfx8 val = *(const halfx8*)(ktb + (size_t)(k0 + key) * C_ + ch * 8);
            *(halfx8*)(&Kt_s[key][ch * 8]) = val;
        }
#pragma unroll
        for (int p = 0; p < 4; ++p) {
            int idx = p * 256 + tid;
            int c  = idx >> 2;
            int ch = idx & 3;
            halfx8 val = *(const halfx8*)(vb + (size_t)c * N_ + k0 + ch * 8);
            *(halfx8*)(&Vs[c][ch * 8]) = val;
        }
        __syncthreads();

        // ---- S = Q^T K  (rows q = quad*4+r, col key = lane15 + 16*ktile) ----
        floatx4 s_acc[2];
        s_acc[0] = (floatx4){0.f, 0.f, 0.f, 0.f};
        s_acc[1] = (floatx4){0.f, 0.f, 0.f, 0.f};
#pragma unroll
        for (int ktile = 0; ktile < 2; ++ktile) {
            const _Float16* krow = &Kt_s[ktile * 16 + lane15][quad * 8];
#pragma unroll
            for (int cs = 0; cs < 8; ++cs) {
                halfx8 bf = *(const halfx8*)(krow + cs * 32);
                s_acc[ktile] = __builtin_amdgcn_mfma_f32_16x16x32_f16(qfrag[cs], bf, s_acc[ktile], 0, 0, 0);
            }
        }

        // ---- online softmax (wave-local; rows live in 16-lane groups) ----
        float rmax[4], psum[4], p0[4], p1[4], alpha[4];
#pragma unroll
        for (int r = 0; r < 4; ++r) rmax[r] = fmaxf(s_acc[0][r], s_acc[1][r]);
#pragma unroll
        for (int mask = 1; mask <= 8; mask <<= 1)
#pragma unroll
            for (int r = 0; r < 4; ++r) rmax[r] = fmaxf(rmax[r], __shfl_xor(rmax[r], mask));
#pragma unroll
        for (int r = 0; r < 4; ++r) {
            float mn = fmaxf(m_r[r], rmax[r]);
            alpha[r] = __expf(m_r[r] - mn);
            m_r[r] = mn;
            p0[r] = __expf(s_acc[0][r] - mn);
            p1[r] = __expf(s_acc[1][r] - mn);
            psum[r] = p0[r] + p1[r];
        }
#pragma unroll
        for (int mask = 1; mask <= 8; mask <<= 1)
#pragma unroll
            for (int r = 0; r < 4; ++r) psum[r] += __shfl_xor(psum[r], mask);
#pragma unroll
        for (int r = 0; r < 4; ++r) l_r[r] = l_r[r] * alpha[r] + psum[r];

        // ---- write P (C-layout -> LDS) and alpha broadcast ----
#pragma unroll
        for (int r = 0; r < 4; ++r) {
            Ps[w][quad * 4 + r][lane15]      = (_Float16)p0[r];
            Ps[w][quad * 4 + r][16 + lane15] = (_Float16)p1[r];
        }
        if (lane15 == 0) {
#pragma unroll
            for (int r = 0; r < 4; ++r) alpha_s[w][quad * 4 + r] = alpha[r];
        }
        __syncthreads();   // bulletproof ordering of LDS write -> cross-lane read

        // ---- rescale O, then O += V * P^T ----
        float av = alpha_s[w][lane15];       // col q = lane15 for all o_acc
#pragma unroll
        for (int i = 0; i < 16; ++i) {
            o_acc[i][0] *= av; o_acc[i][1] *= av; o_acc[i][2] *= av; o_acc[i][3] *= av;
        }
        halfx8 pfrag = *(const halfx8*)(&Ps[w][lane15][quad * 8]);  // B[k=key][n=q]
#pragma unroll
        for (int ct = 0; ct < 16; ++ct) {
            halfx8 vf = *(const halfx8*)(&Vs[ct * 16 + lane15][quad * 8]);  // A[m=c][k=key]
            o_acc[ct] = __builtin_amdgcn_mfma_f32_16x16x32_f16(vf, pfrag, o_acc[ct], 0, 0, 0);
        }
        __syncthreads();   // before restaging K/V
    }

    // ---- epilogue: out = gamma * O/l + x ----
    if (lane15 == 0) {
#pragma unroll
        for (int r = 0; r < 4; ++r) l_s[w][quad * 4 + r] = l_r[r];
    }
    __syncthreads();
    float linv = 1.0f / l_s[w][lane15];
    float g = isf32 ? ((const float*)gamma_p)[0] : bf16_to_f(((const uint16_t*)gamma_p)[0]);
    const int n_out = q0 + w * 16 + lane15;
    if (isf32) {
        const float* xf = (const float*)x_raw;
        float* of = (float*)out;
#pragma unroll
        for (int ct = 0; ct < 16; ++ct)
#pragma unroll
            for (int r = 0; r < 4; ++r) {
                int c = ct * 16 + quad * 4 + r;
                size_t off = ((size_t)b * C_ + c) * N_ + n_out;
                of[off] = g * o_acc[ct][r] * linv + xf[off];
            }
    } else {
        const uint16_t* xu = (const uint16_t*)x_raw;
        uint16_t* ou = (uint16_t*)out;
#pragma unroll
        for (int ct = 0; ct < 16; ++ct)
#pragma unroll
            for (int r = 0; r < 4; ++r) {
                int c = ct * 16 + quad * 4 + r;
                size_t off = ((size_t)b * C_ + c) * N_ + n_out;
                float val = g * o_acc[ct][r] * linv + bf16_to_f(xu[off]);
                ou[off] = f_to_bf16(val);
            }
    }
}

// ---------------- launcher ----------------
extern "C" void kernel_launch(void* const* d_in, const int* in_sizes, int n_in,
                              void* d_out, int out_size, void* d_ws, size_t ws_size,
                              hipStream_t stream) {
    const void* x  = d_in[0];
    const void* wq = d_in[1];
    const void* wk = d_in[2];
    const void* wv = d_in[3];
    const void* gm = d_in[4];

    char* ws = (char*)d_ws;
    int* flag    = (int*)ws;                                       // @0
    _Float16* wf = (_Float16*)(ws + 4096);                         // 384 KB
    _Float16* qt = (_Float16*)(ws + 4096 + 393216);                // 8 MB
    _Float16* kt = (_Float16*)(ws + 4096 + 393216 + 8388608);      // 8 MB
    _Float16* v  = (_Float16*)(ws + 4096 + 393216 + 2 * 8388608);  // 8 MB

    sniff_kernel<<<dim3(1), dim3(256), 0, stream>>>((const uint16_t*)wq, flag);
    wconv_kernel<<<dim3(768), dim3(256), 0, stream>>>(wq, wk, wv, wf, flag);
    proj_kernel<<<dim3(64, 4), dim3(256), 0, stream>>>(x, wf, qt, kt, v, flag);
    attn_kernel<<<dim3(64, 4), dim3(256), 0, stream>>>(x, qt, kt, v, gm, d_out, flag);
}